// Round 8
// baseline (36777.005 us; speedup 1.0000x reference)
//
#include <hip/hip_runtime.h>
#include <math.h>

// Backprop_29188597744223 — 1024-step sequential MLP training scan.
//
//   k_gram : G = X·Xᵀ, grid-parallel
//   k_z10  : Z10 = X·W1_init, grid-parallel
//   k2_seq : ONE workgroup, 512 threads. The toolchain hard-caps VGPRs at
//            65536/threads = 128 (measured R2-R7), so persistent state is
//            sized to fit: W2 rows 0..159 in registers (10 f32x8/thread),
//            rows 160..255 in LDS (thread-private 6x8 tiles), W3 in regs
//            (32 floats). o1 in-block history bf16 in LDS; z1p/G-row/target
//            prefetched one step ahead into LDS ping-pong buffers by idle
//            waves during C2. W1 lazy (Gram trick, ||U1||² in double).
//   k_w1out: W1_final = s1_f·(W1_init + Xᵀ·diag(c)·O1), grid-parallel

#define LRC  0.01f
#define EPSV 1e-8f

typedef float f32x8 __attribute__((ext_vector_type(8)));
typedef unsigned int uint32;

// ---- LDS layout (float offsets) ----
#define W2L_OFF   0        // [96][258] fp32 = 24768
#define W2L_STR   258
#define SCR_OFF   24768    // 4224 floats (B1 [16][264] / EF [256][9] / prefix [16][264])
#define O1H_OFF   28992    // 64*260 ushorts = 8320 floats
#define O1H_STR   260      // in ushorts
#define GST_OFF   37312    // [16][17]
#define A1V_OFF   37584
#define Z1V_OFF   37840
#define Z2V_OFF   38096
#define A2V_OFF   38352
#define O2V_OFF   38608
#define O1V_OFF   38864
#define B1V_OFF   39120
#define B2V_OFF   39376
#define Z3V_OFF   39632
#define D3V_OFF   39696
#define B3V_OFF   39760
#define CH_OFF    39824
#define DTS_OFF   39888
#define CPRE_OFF  39904
#define Z1PRE_OFF 39920    // [2][256]
#define GPRE_OFF  40432    // [2][64]
#define TPRE_OFF  40560    // [2][64]
#define SMEM_FLOATS 40688
#define SMEM_BYTES  (SMEM_FLOATS * 4)   // 162752 B < 160 KiB

#define ROWS10(OP) OP(0) OP(1) OP(2) OP(3) OP(4) OP(5) OP(6) OP(7) OP(8) OP(9)
#define ROWS6(OP)  OP(0) OP(1) OP(2) OP(3) OP(4) OP(5)
#define ROWS16(OP)                                                            \
  OP(0) OP(1) OP(2) OP(3) OP(4) OP(5) OP(6) OP(7)                             \
  OP(8) OP(9) OP(10) OP(11) OP(12) OP(13) OP(14) OP(15)

__device__ __forceinline__ float hsum8(f32x8 v) {
  return ((v.s0 + v.s1) + (v.s2 + v.s3)) + ((v.s4 + v.s5) + (v.s6 + v.s7));
}
__device__ __forceinline__ unsigned short f2bf(float f) {
  uint32 u = __float_as_uint(f);
  return (unsigned short)((u + 0x7FFFu + ((u >> 16) & 1u)) >> 16);
}
__device__ __forceinline__ float bf2f(unsigned short h) {
  return __uint_as_float(((uint32)h) << 16);
}

#define FMA16(c, a, b)                                                        \
  c[0][0] += a.x * b.x; c[0][1] += a.x * b.y; c[0][2] += a.x * b.z; c[0][3] += a.x * b.w; \
  c[1][0] += a.y * b.x; c[1][1] += a.y * b.y; c[1][2] += a.y * b.z; c[1][3] += a.y * b.w; \
  c[2][0] += a.z * b.x; c[2][1] += a.z * b.y; c[2][2] += a.z * b.z; c[2][3] += a.z * b.w; \
  c[3][0] += a.w * b.x; c[3][1] += a.w * b.y; c[3][2] += a.w * b.z; c[3][3] += a.w * b.w;

// ---------------------------------------------------------------- k_gram ----
__global__ __launch_bounds__(256) void k_gram(const float* __restrict__ X,
                                              float* __restrict__ G) {
  const int bi = blockIdx.y, bj = blockIdx.x;
  if (bj > bi) return;
  __shared__ float Xa[32][68];
  __shared__ float Xb[32][68];
  const int tid = threadIdx.x;
  const int tx = tid & 15, ty = tid >> 4;
  float c[4][4] = {};
  for (int k0 = 0; k0 < 1024; k0 += 32) {
    __syncthreads();
    {
      const int row = tid >> 2, kk = (tid & 3) * 8;
      const float* pa = X + (bi * 64 + row) * 1024 + k0 + kk;
      const float4 a0 = *(const float4*)pa;
      const float4 a1 = *(const float4*)(pa + 4);
      Xa[kk + 0][row] = a0.x; Xa[kk + 1][row] = a0.y;
      Xa[kk + 2][row] = a0.z; Xa[kk + 3][row] = a0.w;
      Xa[kk + 4][row] = a1.x; Xa[kk + 5][row] = a1.y;
      Xa[kk + 6][row] = a1.z; Xa[kk + 7][row] = a1.w;
      const float* pb = X + (bj * 64 + row) * 1024 + k0 + kk;
      const float4 b0 = *(const float4*)pb;
      const float4 b1 = *(const float4*)(pb + 4);
      Xb[kk + 0][row] = b0.x; Xb[kk + 1][row] = b0.y;
      Xb[kk + 2][row] = b0.z; Xb[kk + 3][row] = b0.w;
      Xb[kk + 4][row] = b1.x; Xb[kk + 5][row] = b1.y;
      Xb[kk + 6][row] = b1.z; Xb[kk + 7][row] = b1.w;
    }
    __syncthreads();
#pragma unroll
    for (int kk = 0; kk < 32; kk++) {
      const float4 a = *(const float4*)&Xa[kk][ty * 4];
      const float4 b = *(const float4*)&Xb[kk][tx * 4];
      FMA16(c, a, b)
    }
  }
#pragma unroll
  for (int ii = 0; ii < 4; ii++) {
    *(float4*)(G + (bi * 64 + ty * 4 + ii) * 1024 + bj * 64 + tx * 4) =
        make_float4(c[ii][0], c[ii][1], c[ii][2], c[ii][3]);
  }
}

// ----------------------------------------------------------------- k_z10 ----
__global__ __launch_bounds__(256) void k_z10(const float* __restrict__ X,
                                             const float* __restrict__ W1g,
                                             float* __restrict__ Z10) {
  const int bi = blockIdx.y, bj = blockIdx.x;
  __shared__ float At[32][68];
  __shared__ float Bt[32][68];
  const int tid = threadIdx.x;
  const int tx = tid & 15, ty = tid >> 4;
  float c[4][4] = {};
  for (int k0 = 0; k0 < 1024; k0 += 32) {
    __syncthreads();
    {
      const int row = tid >> 2, kk = (tid & 3) * 8;
      const float* pa = X + (bi * 64 + row) * 1024 + k0 + kk;
      const float4 a0 = *(const float4*)pa;
      const float4 a1 = *(const float4*)(pa + 4);
      At[kk + 0][row] = a0.x; At[kk + 1][row] = a0.y;
      At[kk + 2][row] = a0.z; At[kk + 3][row] = a0.w;
      At[kk + 4][row] = a1.x; At[kk + 5][row] = a1.y;
      At[kk + 6][row] = a1.z; At[kk + 7][row] = a1.w;
      const int kr = tid >> 3, j8 = (tid & 7) * 8;
      const float* pb = W1g + (k0 + kr) * 256 + bj * 64 + j8;
      *(float4*)&Bt[kr][j8]     = *(const float4*)pb;
      *(float4*)&Bt[kr][j8 + 4] = *(const float4*)(pb + 4);
    }
    __syncthreads();
#pragma unroll
    for (int kk = 0; kk < 32; kk++) {
      const float4 a = *(const float4*)&At[kk][ty * 4];
      const float4 b = *(const float4*)&Bt[kk][tx * 4];
      FMA16(c, a, b)
    }
  }
#pragma unroll
  for (int ii = 0; ii < 4; ii++) {
    *(float4*)(Z10 + (bi * 64 + ty * 4 + ii) * 256 + bj * 64 + tx * 4) =
        make_float4(c[ii][0], c[ii][1], c[ii][2], c[ii][3]);
  }
}

// --------------------------------------------------------------- k_w1out ----
__global__ __launch_bounds__(256) void k_w1out(
    const float* __restrict__ X, const float* __restrict__ o1g,
    const float* __restrict__ cg, const float* __restrict__ W1g,
    const float* __restrict__ sclg, float* __restrict__ outW1) {
  const int bi = blockIdx.y, bj = blockIdx.x;
  __shared__ float At[32][68];
  __shared__ float Bt[32][68];
  const int tid = threadIdx.x;
  const int tx = tid & 15, ty = tid >> 4;
  float c[4][4] = {};
  for (int k0 = 0; k0 < 1024; k0 += 32) {
    __syncthreads();
    {
      const int kr = tid >> 3, m8 = (tid & 7) * 8;
      const float* pa = X + (k0 + kr) * 1024 + bi * 64 + m8;
      *(float4*)&At[kr][m8]     = *(const float4*)pa;
      *(float4*)&At[kr][m8 + 4] = *(const float4*)(pa + 4);
      const float cs = cg[k0 + kr];
      const float* pb = o1g + (k0 + kr) * 256 + bj * 64 + m8;
      float4 b0 = *(const float4*)pb;
      float4 b1 = *(const float4*)(pb + 4);
      b0.x *= cs; b0.y *= cs; b0.z *= cs; b0.w *= cs;
      b1.x *= cs; b1.y *= cs; b1.z *= cs; b1.w *= cs;
      *(float4*)&Bt[kr][m8]     = b0;
      *(float4*)&Bt[kr][m8 + 4] = b1;
    }
    __syncthreads();
#pragma unroll
    for (int kk = 0; kk < 32; kk++) {
      const float4 a = *(const float4*)&At[kk][ty * 4];
      const float4 b = *(const float4*)&Bt[kk][tx * 4];
      FMA16(c, a, b)
    }
  }
  const float s1f = sclg[0];
#pragma unroll
  for (int ii = 0; ii < 4; ii++) {
    const int row = bi * 64 + ty * 4 + ii;
    const float4 w = *(const float4*)(W1g + row * 256 + bj * 64 + tx * 4);
    *(float4*)(outW1 + row * 256 + bj * 64 + tx * 4) =
        make_float4(s1f * (w.x + c[ii][0]), s1f * (w.y + c[ii][1]),
                    s1f * (w.z + c[ii][2]), s1f * (w.w + c[ii][3]));
  }
}

// ---------------------------------------------------------------- k2_seq ----
__device__ __forceinline__ float block_reduce8(float v, float* tmp, int tid) {
#pragma unroll
  for (int off = 32; off > 0; off >>= 1) v += __shfl_xor(v, off);
  __syncthreads();
  if ((tid & 63) == 0) tmp[tid >> 6] = v;
  __syncthreads();
  float s = 0.f;
#pragma unroll
  for (int w = 0; w < 8; w++) s += tmp[w];
  __syncthreads();
  return s;
}

__global__ __launch_bounds__(512) void k2_seq(
    const float* __restrict__ Tg, const float* __restrict__ W1g,
    const float* __restrict__ b1g, const float* __restrict__ W2g,
    const float* __restrict__ b2g, const float* __restrict__ W3g,
    const float* __restrict__ b3g, const float* __restrict__ G,
    const float* __restrict__ Z10, float* __restrict__ o1g,
    float* __restrict__ cg, float* __restrict__ z1pg,
    float* __restrict__ sclg, float* __restrict__ outW2,
    float* __restrict__ outW3) {
  extern __shared__ float sm[];
  const int tid = threadIdx.x;
  const int p = tid >> 5;  // 0..15
  const int q = tid & 31;  // 0..31

  // Persistent register state: W2 rows p*10..p*10+9 (cols q*8..+7), W3 16x2.
  f32x8 W2_0, W2_1, W2_2, W2_3, W2_4, W2_5, W2_6, W2_7, W2_8, W2_9;
  float W3x_0, W3x_1, W3x_2, W3x_3, W3x_4, W3x_5, W3x_6, W3x_7,
        W3x_8, W3x_9, W3x_10, W3x_11, W3x_12, W3x_13, W3x_14, W3x_15;
  float W3y_0, W3y_1, W3y_2, W3y_3, W3y_4, W3y_5, W3y_6, W3y_7,
        W3y_8, W3y_9, W3y_10, W3y_11, W3y_12, W3y_13, W3y_14, W3y_15;

#define IW2(i) W2_##i = *(const f32x8*)(W2g + (p * 10 + i) * 256 + q * 8);
  ROWS10(IW2)
#define IW3(i)                                                                \
  { const int row = p * 16 + i;                                               \
    W3x_##i = W3g[row * 64 + q * 2];                                          \
    W3y_##i = W3g[row * 64 + q * 2 + 1]; }
  ROWS16(IW3)

  float acc2 = 0.f;
  // W2 LDS rows 160..255: thread-private 6-row x 8-col tile.
#define IW2L(i)                                                               \
  { f32x8 tv = *(const f32x8*)(W2g + (160 + p * 6 + i) * 256 + q * 8);        \
    *(f32x8*)(sm + W2L_OFF + (p * 6 + i) * W2L_STR + q * 8) = tv;             \
    f32x8 t2 = tv * tv; acc2 += hsum8(t2); }
  ROWS6(IW2L)
#define N2R(i) { f32x8 t2 = W2_##i * W2_##i; acc2 += hsum8(t2); }
  ROWS10(N2R)

  if (tid < 256) { sm[B1V_OFF + tid] = b1g[tid]; sm[B2V_OFF + tid] = b2g[tid]; }
  if (tid < 64) sm[B3V_OFF + tid] = b3g[tid];

  float acc1 = 0.f;
  for (int i = tid; i < 65536; i += 512) {
    const float4 v = ((const float4*)W1g)[i];
    acc1 += v.x * v.x + v.y * v.y + v.z * v.z + v.w * v.w;
  }
  __syncthreads();
  const float n1init = block_reduce8(acc1, sm + SCR_OFF, tid);
  const float n2init = block_reduce8(acc2, sm + SCR_OFF, tid);
  float acc3 = 0.f;
#define N3R(i) acc3 += W3x_##i * W3x_##i + W3y_##i * W3y_##i;
  ROWS16(N3R)
  const float n3init = block_reduce8(acc3, sm + SCR_OFF, tid);

  float s1 = 1.f;
  double n1d = (double)n1init;
  float n2 = n2init, n3 = n3init;
  __syncthreads();

  for (int b = 0; b < 16; b++) {
    const int bs = b * 64;
    // ---- prefix (4 passes x 16 rows): z1pg[r] = Z10[bs+r] + sum cg*G*o1
    for (int v = 0; v < 4; v++) {
      f32x8 pacc = {0.f, 0.f, 0.f, 0.f, 0.f, 0.f, 0.f, 0.f};
      const int rv = v * 16 + p;
      for (int c0 = 0; c0 < bs; c0 += 16) {
        __syncthreads();
        {
          const int sr = tid >> 5, j8 = (tid & 31) * 8;
          *(f32x8*)(sm + SCR_OFF + sr * 264 + j8) =
              *(const f32x8*)(o1g + (c0 + sr) * 256 + j8);
        }
        if (tid < 256) {
          const int rr = tid >> 4, ss = tid & 15;
          sm[GST_OFF + rr * 17 + ss] =
              G[(bs + v * 16 + rr) * 1024 + c0 + ss];
        }
        if (tid < 16) sm[CPRE_OFF + tid] = cg[c0 + tid];
        __syncthreads();
#pragma unroll
        for (int ss = 0; ss < 16; ss++) {
          const float g = sm[GST_OFF + p * 17 + ss] * sm[CPRE_OFF + ss];
          pacc += g * (*(const f32x8*)(sm + SCR_OFF + ss * 264 + q * 8));
        }
      }
      *(f32x8*)(z1pg + rv * 256 + q * 8) =
          *(const f32x8*)(Z10 + (bs + rv) * 256 + q * 8) + pacc;
    }
    // ---- prime prefetch slot 0 (z1p row 0, G-diag row 0, targets row 0)
    __syncthreads();
    if (tid < 256) sm[Z1PRE_OFF + tid] = z1pg[tid];
    else if (tid < 320) sm[GPRE_OFF + (tid - 256)] = G[bs * 1024 + bs + (tid - 256)];
    else if (tid < 384) sm[TPRE_OFF + (tid - 320)] = Tg[bs * 64 + (tid - 320)];
    __syncthreads();

    // ---- 64 sequential steps
    for (int l = 0; l < 64; l++) {
      const int t = bs + l;
      const int cur = l & 1, nxt = cur ^ 1;
      const float* z1cur = sm + Z1PRE_OFF + cur * 256;
      const float* gcur  = sm + GPRE_OFF + cur * 64;
      const float* tcur  = sm + TPRE_OFF + cur * 64;
      // A: z1u = z1p[l] + in-block history (bf16); a1 = sigmoid(s1*z1u + b1)
      {
        const int j = tid >> 1, half = tid & 1;
        const unsigned short* o1h = (const unsigned short*)(sm + O1H_OFF);
        float a = 0.f;
        for (int lp = half; lp < l; lp += 2)
          a += sm[CH_OFF + lp] * gcur[lp] * bf2f(o1h[lp * O1H_STR + j]);
        a += __shfl_xor(a, 1);
        if (half == 0) {
          const float z1u = z1cur[j] + a;
          sm[Z1V_OFF + j] = z1u;
          sm[A1V_OFF + j] = 1.f / (1.f + expf(-(s1 * z1u + sm[B1V_OFF + j])));
        }
      }
      __syncthreads();
      // B1: z2 col-partials = a1 @ W2 (reg rows + LDS rows)
      {
        f32x8 acc = {0.f, 0.f, 0.f, 0.f, 0.f, 0.f, 0.f, 0.f};
#define B1R(i) acc += sm[A1V_OFF + p * 10 + i] * W2_##i;
        ROWS10(B1R)
#define B1L(i)                                                                \
        acc += sm[A1V_OFF + 160 + p * 6 + i] *                                \
               (*(const f32x8*)(sm + W2L_OFF + (p * 6 + i) * W2L_STR + q * 8));
        ROWS6(B1L)
        *(f32x8*)(sm + SCR_OFF + p * 264 + q * 8) = acc;
      }
      __syncthreads();
      // B2
      if (tid < 256) {
        float s = 0.f;
#pragma unroll
        for (int pp = 0; pp < 16; pp++) s += sm[SCR_OFF + pp * 264 + tid];
        sm[Z2V_OFF + tid] = s;
        sm[A2V_OFF + tid] = 1.f / (1.f + expf(-(s + sm[B2V_OFF + tid])));
      }
      __syncthreads();
      // C1: z3 partials = a2 @ W3
      {
        float c0a = 0.f, c1a = 0.f;
#define C1R(i)                                                                \
        { const float a2x = sm[A2V_OFF + p * 16 + i];                         \
          c0a += a2x * W3x_##i; c1a += a2x * W3y_##i; }
        ROWS16(C1R)
        sm[SCR_OFF + (q * 2 + 0) * 17 + p] = c0a;
        sm[SCR_OFF + (q * 2 + 1) * 17 + p] = c1a;
      }
      __syncthreads();
      // C2 (wave 0) + prefetch next step's z1p/G-row/targets (waves 1-6)
      if (tid < 64) {
        float s = 0.f;
#pragma unroll
        for (int pp = 0; pp < 16; pp++) s += sm[SCR_OFF + tid * 17 + pp];
        sm[Z3V_OFF + tid] = s;
        const float a3 = 1.f / (1.f + expf(-(s + sm[B3V_OFF + tid])));
        const float e = expf(-a3);
        float tot = e;
#pragma unroll
        for (int off = 32; off > 0; off >>= 1) tot += __shfl_xor(tot, off);
        const float outv = e / tot;
        const float d3 = (tcur[tid] - outv) * a3 * (1.f - a3);
        sm[D3V_OFF + tid] = d3;
        sm[B3V_OFF + tid] = sm[B3V_OFF + tid] - LRC * d3;
      } else if (tid < 320) {
        const int j = tid - 64, ln = (l + 1 < 64) ? l + 1 : 63;
        sm[Z1PRE_OFF + nxt * 256 + j] = z1pg[ln * 256 + j];
      } else if (tid < 384) {
        const int j = tid - 320, ln = (l + 1 < 64) ? l + 1 : 63;
        sm[GPRE_OFF + nxt * 64 + j] = G[(bs + ln) * 1024 + bs + j];
      } else if (tid < 448) {
        const int j = tid - 384, ln = (l + 1 < 64) ? l + 1 : 63;
        sm[TPRE_OFF + nxt * 64 + j] = Tg[(bs + ln) * 64 + j];
      }
      __syncthreads();
      // E1: o2 partials = W3 @ d3, 4-way shuffle-combined
      {
        const float d0 = sm[D3V_OFF + q * 2], d1 = sm[D3V_OFF + q * 2 + 1];
#define E1R(i)                                                                \
        { float e = W3x_##i * d0 + W3y_##i * d1;                              \
          e += __shfl_xor(e, 1); e += __shfl_xor(e, 2);                       \
          if ((q & 3) == 0)                                                   \
            sm[SCR_OFF + (p * 16 + i) * 9 + (q >> 2)] = e; }
        ROWS16(E1R)
      }
      __syncthreads();
      // E2
      if (tid < 256) {
        float s = 0.f;
#pragma unroll
        for (int g = 0; g < 8; g++) s += sm[SCR_OFF + tid * 9 + g];
        const float a2x = sm[A2V_OFF + tid];
        const float o2 = s * a2x * (1.f - a2x);
        sm[O2V_OFF + tid] = o2;
        sm[B2V_OFF + tid] = sm[B2V_OFF + tid] - LRC * o2;
      }
      __syncthreads();
      // F1: o1 row-dots = W2 @ o2 (reg rows + LDS rows), 4-way combined
      {
        const f32x8 ov8 = *(const f32x8*)(sm + O2V_OFF + q * 8);
#define F1R(i)                                                                \
        { f32x8 tmp = W2_##i * ov8; float e = hsum8(tmp);                     \
          e += __shfl_xor(e, 1); e += __shfl_xor(e, 2);                       \
          if ((q & 3) == 0)                                                   \
            sm[SCR_OFF + (p * 10 + i) * 9 + (q >> 2)] = e; }
        ROWS10(F1R)
#define F1L(i)                                                                \
        { f32x8 w = *(const f32x8*)(sm + W2L_OFF + (p * 6 + i) * W2L_STR + q * 8); \
          f32x8 tmp = w * ov8; float e = hsum8(tmp);                          \
          e += __shfl_xor(e, 1); e += __shfl_xor(e, 2);                       \
          if ((q & 3) == 0)                                                   \
            sm[SCR_OFF + (160 + p * 6 + i) * 9 + (q >> 2)] = e; }
        ROWS6(F1L)
      }
      __syncthreads();
      // F2
      if (tid < 256) {
        float s = 0.f;
#pragma unroll
        for (int g = 0; g < 8; g++) s += sm[SCR_OFF + tid * 9 + g];
        const float a1x = sm[A1V_OFF + tid];
        const float o1x = s * a1x * (1.f - a1x);
        sm[O1V_OFF + tid] = o1x;
        ((unsigned short*)(sm + O1H_OFF))[l * O1H_STR + tid] = f2bf(o1x);
        o1g[t * 256 + tid] = o1x;
        sm[B1V_OFF + tid] = sm[B1V_OFF + tid] - LRC * o1x;
      }
      __syncthreads();
      // G: batched dots (8 waves, 11 dots over two rounds)
      {
        const int w = tid >> 6, lane = tid & 63;
        float v = 0.f;
        if (w == 0)      { for (int i = lane; i < 256; i += 64) v += sm[Z1V_OFF+i] * sm[O1V_OFF+i]; }
        else if (w == 1) { for (int i = lane; i < 256; i += 64) v += sm[O1V_OFF+i] * sm[O1V_OFF+i]; }
        else if (w == 2) { for (int i = lane; i < 256; i += 64) v += sm[Z2V_OFF+i] * sm[O2V_OFF+i]; }
        else if (w == 3) { for (int i = lane; i < 256; i += 64) v += sm[A1V_OFF+i] * sm[A1V_OFF+i]; }
        else if (w == 4) { for (int i = lane; i < 256; i += 64) v += sm[O2V_OFF+i] * sm[O2V_OFF+i]; }
        else if (w == 5) { v = sm[Z3V_OFF+lane] * sm[D3V_OFF+lane]; }
        else if (w == 6) { for (int i = lane; i < 256; i += 64) v += sm[A2V_OFF+i] * sm[A2V_OFF+i]; }
        else             { v = sm[D3V_OFF+lane] * sm[D3V_OFF+lane]; }
#pragma unroll
        for (int off = 32; off > 0; off >>= 1) v += __shfl_xor(v, off);
        if (lane == 0) sm[DTS_OFF + w] = v;
        float v2 = 0.f;
        if (w == 0)      { for (int i = lane; i < 256; i += 64) v2 += sm[B1V_OFF+i] * sm[B1V_OFF+i]; }
        else if (w == 1) { for (int i = lane; i < 256; i += 64) v2 += sm[B2V_OFF+i] * sm[B2V_OFF+i]; }
        else if (w == 2) { v2 = sm[B3V_OFF+lane] * sm[B3V_OFF+lane]; }
#pragma unroll
        for (int off = 32; off > 0; off >>= 1) v2 += __shfl_xor(v2, off);
        if (lane == 0 && w < 3) sm[DTS_OFF + 8 + w] = v2;
      }
      __syncthreads();
      // H: replicated recurrences + rank-1 updates + renorm
      {
        const float c1 = -LRC / s1;
        const double gtt = (double)gcur[l];
        const double n1 = n1d + 2.0 * (double)c1 * (double)sm[DTS_OFF + 0] +
                          (double)c1 * (double)c1 * gtt * (double)sm[DTS_OFF + 1];
        n1d = n1;
        const double w1n = (double)s1 * sqrt(n1);
        s1 = (float)((double)s1 / fmax(w1n, (double)EPSV));
        if (tid == 0) { sm[CH_OFF + l] = c1; cg[t] = c1; }
        const float n2p = n2 - 2.f * LRC * sm[DTS_OFF + 2] +
                          LRC * LRC * sm[DTS_OFF + 3] * sm[DTS_OFF + 4];
        const float r2s = 1.f / fmaxf(sqrtf(n2p), EPSV);
        n2 = n2p * r2s * r2s;
        const float n3p = n3 - 2.f * LRC * sm[DTS_OFF + 5] +
                          LRC * LRC * sm[DTS_OFF + 6] * sm[DTS_OFF + 7];
        const float r3s = 1.f / fmaxf(sqrtf(n3p), EPSV);
        n3 = n3p * r3s * r3s;
        const float rb1 = 1.f / fmaxf(sqrtf(sm[DTS_OFF + 8]), EPSV);
        const float rb2 = 1.f / fmaxf(sqrtf(sm[DTS_OFF + 9]), EPSV);
        const float rb3 = 1.f / fmaxf(sqrtf(sm[DTS_OFF + 10]), EPSV);

        const f32x8 ovs = (-LRC * r2s) * (*(const f32x8*)(sm + O2V_OFF + q * 8));
        const float d0s = -LRC * r3s * sm[D3V_OFF + q * 2];
        const float d1s = -LRC * r3s * sm[D3V_OFF + q * 2 + 1];
#define HR(i)                                                                 \
        { const float a1x = sm[A1V_OFF + p * 10 + i];                         \
          W2_##i = W2_##i * r2s + a1x * ovs; }
        ROWS10(HR)
#define HL(i)                                                                 \
        { float* wp = sm + W2L_OFF + (p * 6 + i) * W2L_STR + q * 8;           \
          f32x8 w = *(const f32x8*)wp;                                        \
          const float a1x = sm[A1V_OFF + 160 + p * 6 + i];                    \
          *(f32x8*)wp = w * r2s + a1x * ovs; }
        ROWS6(HL)
#define HW3(i)                                                                \
        { const float a2x = sm[A2V_OFF + p * 16 + i];                         \
          W3x_##i = W3x_##i * r3s + a2x * d0s;                                \
          W3y_##i = W3y_##i * r3s + a2x * d1s; }
        ROWS16(HW3)
        if (tid < 256) {
          sm[B1V_OFF + tid] *= rb1;
          sm[B2V_OFF + tid] *= rb2;
        }
        if (tid < 64) sm[B3V_OFF + tid] *= rb3;
      }
      __syncthreads();
    }
  }

  if (tid == 0) sclg[0] = s1;
#define OW2(i) *(f32x8*)(outW2 + (p * 10 + i) * 256 + q * 8) = W2_##i;
  ROWS10(OW2)
#define OW2L(i)                                                               \
  *(f32x8*)(outW2 + (160 + p * 6 + i) * 256 + q * 8) =                        \
      *(const f32x8*)(sm + W2L_OFF + (p * 6 + i) * W2L_STR + q * 8);
  ROWS6(OW2L)
#define OW3(i)                                                                \
  { const int row = p * 16 + i;                                               \
    outW3[row * 64 + q * 2] = W3x_##i;                                        \
    outW3[row * 64 + q * 2 + 1] = W3y_##i; }
  ROWS16(OW3)
}

// ---------------------------------------------------------------- launch ----
extern "C" void kernel_launch(void* const* d_in, const int* in_sizes, int n_in,
                              void* d_out, int out_size, void* d_ws,
                              size_t ws_size, hipStream_t stream) {
  (void)in_sizes; (void)n_in; (void)out_size; (void)ws_size;
  const float* X   = (const float*)d_in[0];
  const float* Tg  = (const float*)d_in[1];
  const float* W1g = (const float*)d_in[2];
  const float* b1g = (const float*)d_in[3];
  const float* W2g = (const float*)d_in[4];
  const float* b2g = (const float*)d_in[5];
  const float* W3g = (const float*)d_in[6];
  const float* b3g = (const float*)d_in[7];
  float* out = (float*)d_out;
  float* ws  = (float*)d_ws;

  float* G    = ws;                  // 1048576
  float* Z10  = G + 1048576;         // 262144
  float* o1g  = Z10 + 262144;        // 262144
  float* cg   = o1g + 262144;        // 1024
  float* sclg = cg + 1024;           // 8
  float* z1pg = sclg + 8;            // 16384 (block-local z1p rows)

  (void)hipFuncSetAttribute((const void*)k2_seq,
                            hipFuncAttributeMaxDynamicSharedMemorySize,
                            SMEM_BYTES);

  k_gram<<<dim3(16, 16), 256, 0, stream>>>(X, G);
  k_z10<<<dim3(4, 16), 256, 0, stream>>>(X, W1g, Z10);
  k2_seq<<<dim3(1), dim3(512), SMEM_BYTES, stream>>>(
      Tg, W1g, b1g, W2g, b2g, W3g, b3g, G, Z10, o1g, cg, z1pg, sclg,
      out + 262144, out + 327680);
  k_w1out<<<dim3(4, 16), 256, 0, stream>>>(X, o1g, cg, W1g, sclg, out);
}